// Round 23
// baseline (3357.524 us; speedup 1.0000x reference)
//
#include <hip/hip_runtime.h>

// LSTM H=512, B=256, T=256, D_IN=10, C=10. fp32 in/out.
// R23 = R22 + staging-batch fix. R22 post-mortem: VGPR=36 proved the compiler
// interleaved the 16 staging loads with panel writes -> 16 serialized L3
// round-trips/thread/step (~11us) = the 3x regression. Fix: a compiler memory
// barrier between the load block and the panel-write block pins program order
// -> all 16 agent loads in flight, ONE exposed L3 latency. Rest identical:
// 256 WGs = 64 rg x 4 ct; WG = 32 rows x 64 cols, 512 thr (8 waves, 2/SIMD);
// 3 barriers/step, single flag set, LDS 139.8KB -> 1 WG/CU.

#define Hdim 512
#define Bdim 256
#define Tdim 256
#define Kpad 544          // 512 (h) + 32 (x: 10 real + 22 zero)
#define LROW 548          // weight LDS row stride (shorts)
#define PROW 536          // panel LDS col stride (shorts)
#define LDS_BYTES ((32 * LROW * 2 + 64 * PROW + 512) * 2)   // 139,776 B -> 1 WG/CU

typedef __bf16 bf16x8 __attribute__((ext_vector_type(8)));
typedef float f32x4 __attribute__((ext_vector_type(4)));
typedef unsigned long long u64;

__device__ __forceinline__ unsigned short f2bf(float f) {
    union { float f; unsigned u; } x; x.f = f;
    unsigned r = x.u + 0x7FFFu + ((x.u >> 16) & 1u);
    return (unsigned short)(r >> 16);
}
__device__ __forceinline__ float bf2f(unsigned short h) {
    union { unsigned u; float f; } x; x.u = ((unsigned)h) << 16;
    return x.f;
}
__device__ __forceinline__ bf16x8 ld8(const unsigned short* p) {
    return *reinterpret_cast<const bf16x8*>(p);
}
__device__ __forceinline__ u64 ldA(const u64* p) {   // coherent 8B load (L3)
    return __hip_atomic_load(p, __ATOMIC_RELAXED, __HIP_MEMORY_SCOPE_AGENT);
}
// write-through 4B store (agent scope -> lands at coherence point)
__device__ __forceinline__ void stH32(unsigned* p, unsigned v) {
    __hip_atomic_store(p, v, __ATOMIC_RELAXED, __HIP_MEMORY_SCOPE_AGENT);
}
__device__ __forceinline__ f32x4 mfma16(bf16x8 a, bf16x8 b, f32x4 c) {
    return __builtin_amdgcn_mfma_f32_16x16x32_bf16(a, b, c, 0, 0, 0);
}
__device__ __forceinline__ bf16x8 pack2(u64 a, u64 b) {
    union { u64 q[2]; bf16x8 v; } u; u.q[0] = a; u.q[1] = b; return u.v;
}
__device__ __forceinline__ float sigm(float x) { return 1.f / (1.f + __expf(-x)); }
__device__ __forceinline__ float tanh_fast(float x) {
    return 2.f / (1.f + __expf(-2.f * x)) - 1.f;
}
// 64-lane parallel poll of the col-group's 64 flag lines, bounded, hot first try
__device__ __forceinline__ void poll64(const unsigned* pollp, unsigned tgt) {
    unsigned v = __hip_atomic_load(pollp, __ATOMIC_RELAXED, __HIP_MEMORY_SCOPE_AGENT);
    bool ok = (v >= tgt);
    int guard = 1 << 16;   // bounded: pathological case -> no hang
    while (!ok && --guard) {
        __builtin_amdgcn_s_sleep(1);
        v = __hip_atomic_load(pollp, __ATOMIC_RELAXED, __HIP_MEMORY_SCOPE_AGENT);
        ok = (v >= tgt);
    }
}

// ---------- prep: stacked gate weights -> bf16 hi/lo, row = 4*i + gate ----------
__global__ void k_prep_w(const float* __restrict__ w_gh, const float* __restrict__ w_ih,
                         const float* __restrict__ w_fh, const float* __restrict__ w_oh,
                         const float* __restrict__ w_gx, const float* __restrict__ w_ix,
                         const float* __restrict__ w_fx, const float* __restrict__ w_ox,
                         unsigned short* __restrict__ Whi, unsigned short* __restrict__ Wlo) {
    int idx = blockIdx.x * 256 + threadIdx.x;
    if (idx >= 2048 * Kpad) return;
    int rw = idx / Kpad;
    int k  = idx % Kpad;
    int gate = rw & 3;
    int i = rw >> 2;
    float v = 0.f;
    if (k < 512) {
        const float* wh = (gate == 0) ? w_gh : (gate == 1) ? w_ih : (gate == 2) ? w_fh : w_oh;
        v = wh[i * 512 + k];
    } else if (k < 522) {
        const float* wx = (gate == 0) ? w_gx : (gate == 1) ? w_ix : (gate == 2) ? w_fx : w_ox;
        v = wx[i * 10 + (k - 512)];
    }
    unsigned short hi = f2bf(v);
    unsigned short lo = f2bf(v - bf2f(hi));
    Whi[idx] = hi;
    Wlo[idx] = lo;
}

// ---------- prep: x -> Xhi/Xlo [t][b][32] ----------
__global__ void k_prep_x(const float* __restrict__ x,
                         unsigned short* __restrict__ Xhi, unsigned short* __restrict__ Xlo) {
    int idx = blockIdx.x * 256 + threadIdx.x;
    if (idx >= Tdim * Bdim * 32) return;
    int j = idx & 31;
    int b = (idx >> 5) & 255;
    int t = idx >> 13;
    float v = 0.f;
    if (j < 10) v = x[(b * Tdim + t) * 10 + j];
    unsigned short hi = f2bf(v);
    unsigned short lo = f2bf(v - bf2f(hi));
    Xhi[idx] = hi;
    Xlo[idx] = lo;
}

__global__ void k_zero(float* __restrict__ p) {
    p[blockIdx.x * 256 + threadIdx.x] = 0.f;
}

// ---------- persistent LSTM ----------
// 256 WGs x 512 thr. WG: 32 stacked rows x 64 cols. Wave (wm,wn): rows
// wm*16..+15, cols wn*16..+15. Lane: cell (i0 = rg*8+wm*4+q, colc).
// h layout: Hc[(ct*64+rg)*512 + c_local*8 + i0%8] -> 1KB/WG contiguous.
__global__ __launch_bounds__(512, 1) void k_persist(
    const unsigned short* __restrict__ Whi, const unsigned short* __restrict__ Wlo,
    const unsigned short* __restrict__ Xhi, const unsigned short* __restrict__ Xlo,
    unsigned short* H0c, unsigned short* H1c,
    float* __restrict__ Hf32,
    const float* __restrict__ bg, const float* __restrict__ bi,
    const float* __restrict__ bf_, const float* __restrict__ bo,
    unsigned* flags) {
    extern __shared__ unsigned short lds[];
    unsigned short* Lhi = lds;                       // [32][LROW]
    unsigned short* Llo = lds + 32 * LROW;           // [32][LROW]
    unsigned short* Pp  = lds + 32 * LROW * 2;       // [64][PROW] panel
    unsigned short* Ho  = Pp + 64 * PROW;            // [64][8] h-out bounce

    const int bid = blockIdx.x;
    const int rg  = bid >> 2;                  // row-group id (0..63)
    const int m0  = rg * 32;                   // stacked-row tile base
    const int ct  = bid & 3;                   // column-group id (0..3)
    const int bn0 = ct * 64;
    const int tid = threadIdx.x;
    const int lane = tid & 63;
    const int w  = tid >> 6;                   // wave id 0..7
    const int wm = w >> 2;                     // row position (0..1)
    const int wn = w & 3;                      // col position (0..3)
    const int lr = lane & 15, q = lane >> 4;

    // flags: one 64B line per WG: index (ct*64+rg)*16 uints
    unsigned* myflag = flags + (((ct << 6) + rg) << 4);
    const unsigned* pollp = flags + (((ct << 6) + lane) << 4);  // lane l -> WG (ct,l)

    // panel staging role: thread (cl = tid>>3 col 0..63, e = tid&7)
    const int cl = tid >> 3;
    const int e  = tid & 7;

    // one-time weight staging global -> LDS (32 rows x 544)
    for (int it = tid; it < 32 * 68; it += 512) {
        int r = it / 68, c8 = (it % 68) * 8;
        *(bf16x8*)&Lhi[r * LROW + c8] = ld8(Whi + (size_t)(m0 + r) * Kpad + c8);
        *(bf16x8*)&Llo[r * LROW + c8] = ld8(Wlo + (size_t)(m0 + r) * Kpad + c8);
    }
    __syncthreads();

    const int kq = q * 8;
    const int colc = bn0 + wn * 16 + lr;       // this lane's column
    const int i0 = rg * 8 + wm * 4 + q;        // this lane's h-row
    const int i08 = wm * 4 + q;                // i0 % 8
    const int c_local = wn * 16 + lr;          // col within WG (0..63)

    float c0 = 0.f;
    const f32x4 binit = { bg[i0], bi[i0], bf_[i0], bo[i0] };

    const unsigned short* Ah = &Lhi[(wm * 16 + lr) * LROW + kq];
    const unsigned short* Al = &Llo[(wm * 16 + lr) * LROW + kq];
    const unsigned short* Bl = &Pp[c_local * PROW + kq];

    // global h block base (compact layout): this WG's 1KB block
    const size_t myblk = ((size_t)ct * 64 + rg) * 512;

    for (int t = 0; t < Tdim; ++t) {
        const unsigned short* Rh = (t & 1) ? H1c : H0c;   // holds h(t-1)
        unsigned short* Whc = (t & 1) ? H0c : H1c;        // receives h(t)
        // ---- 1. gate: all 64 producer WGs of this ct posted flag >= t ----
        poll64(pollp, (unsigned)t);

        // ---- 2. staging: ALL 16 loads issued before any LDS write ----
        u64 s[8][2];
#pragma unroll
        for (int j = 0; j < 8; ++j) {
            const int rgp = j * 8 + e;
            const u64* sp = (const u64*)(Rh + (((size_t)ct * 64 + rgp) * 512 + cl * 8));
            s[j][0] = ldA(sp);
            s[j][1] = ldA(sp + 1);
        }
        const unsigned short* xb  = Xhi + ((size_t)t * Bdim + colc) * 32 + kq;
        const unsigned short* xbl = Xlo + ((size_t)t * Bdim + colc) * 32 + kq;
        bf16x8 xh = ld8(xb), xl = ld8(xbl);
        // pin program order: no panel write may be hoisted between the loads
        // (R22 bug: compiler interleaved load->write pairs = 16 serial L3 trips)
        asm volatile("" ::: "memory");
        // panel write: position i = rgp*8..+7 of column cl
#pragma unroll
        for (int j = 0; j < 8; ++j) {
            const int rgp = j * 8 + e;
            *(bf16x8*)&Pp[cl * PROW + rgp * 8] = pack2(s[j][0], s[j][1]);
        }
        __syncthreads();                       // S1: panel ready

        // ---- 3. MFMA: 16 kb x (hi+lo) + x tail, single accumulator ----
        f32x4 acc = binit;
#pragma unroll
        for (int kb = 0; kb < 16; ++kb) {
            const int k = kb * 32;
            bf16x8 ah = ld8(Ah + k), al = ld8(Al + k);
            bf16x8 bh = ld8(Bl + k);
            acc = mfma16(ah, bh, acc);
            acc = mfma16(al, bh, acc);
        }
        {   // x tail
            bf16x8 ah = ld8(Ah + 512), al = ld8(Al + 512);
            acc = mfma16(ah, xh, acc);
            acc = mfma16(ah, xl, acc);
            acc = mfma16(al, xh, acc);
        }

        // ---- 4. epilogue: cell (i0, colc) -> Ho bounce ----
        {
            float g = tanh_fast(acc[0]), ii = sigm(acc[1]);
            float f = sigm(acc[2]),      o  = sigm(acc[3]);
            c0 = g * ii + c0 * f;
            float h = tanh_fast(c0) * o;
            Ho[c_local * 8 + i08] = f2bf(h);
            if (t == Tdim - 1) Hf32[(size_t)colc * Hdim + i0] = h;
        }
        __syncthreads();                       // S2: Ho complete; panel consumed

        // ---- 5. coalesced write-through store: 1KB/WG, threads 0-255 ----
        if (tid < 256)
            stH32((unsigned*)(Whc + myblk) + tid, ((const unsigned*)Ho)[tid]);
        __syncthreads();                       // S3: stores drained (per-wave vmcnt)

        // ---- 6. post flag(t+1) ----
        if (tid == 0)
            __hip_atomic_store(myflag, (unsigned)(t + 1),
                               __ATOMIC_RELAXED, __HIP_MEMORY_SCOPE_AGENT);
    }
}

// ---------- output: logits + softmax, one block per batch element ----------
__global__ __launch_bounds__(64) void k_out(
    const float* __restrict__ Hf32, const float* __restrict__ w_out,
    const float* __restrict__ b_out, float* __restrict__ out) {
    int b = blockIdx.x;
    int lane = threadIdx.x;
    const f32x4* h4 = (const f32x4*)(Hf32 + (size_t)b * 512);
    f32x4 h0 = h4[lane * 2], h1 = h4[lane * 2 + 1];
    float acc[10];
#pragma unroll
    for (int c = 0; c < 10; ++c) {
        const f32x4* w4 = (const f32x4*)(w_out + c * 512);
        f32x4 w0 = w4[lane * 2], w1 = w4[lane * 2 + 1];
        acc[c] = h0[0]*w0[0] + h0[1]*w0[1] + h0[2]*w0[2] + h0[3]*w0[3]
               + h1[0]*w1[0] + h1[1]*w1[1] + h1[2]*w1[2] + h1[3]*w1[3];
    }
#pragma unroll
    for (int s = 32; s >= 1; s >>= 1)
#pragma unroll
        for (int c = 0; c < 10; ++c) acc[c] += __shfl_xor(acc[c], s, 64);
    if (lane == 0) {
        float logit[10];
#pragma unroll
        for (int c = 0; c < 10; ++c) logit[c] = acc[c] + b_out[c];
        float m = logit[0];
#pragma unroll
        for (int c = 1; c < 10; ++c) m = fmaxf(m, logit[c]);
        float e[10], sum = 0.f;
#pragma unroll
        for (int c = 0; c < 10; ++c) { e[c] = __expf(logit[c] - m); sum += e[c]; }
        float inv = 1.f / sum;
#pragma unroll
        for (int c = 0; c < 10; ++c) out[b * 10 + c] = e[c] * inv;
    }
}

extern "C" void kernel_launch(void* const* d_in, const int* in_sizes, int n_in,
                              void* d_out, int out_size, void* d_ws, size_t ws_size,
                              hipStream_t stream) {
    const float* x    = (const float*)d_in[0];
    const float* w_gx = (const float*)d_in[1];
    const float* w_gh = (const float*)d_in[2];
    const float* b_g  = (const float*)d_in[3];
    const float* w_ix = (const float*)d_in[4];
    const float* w_ih = (const float*)d_in[5];
    const float* b_i  = (const float*)d_in[6];
    const float* w_fx = (const float*)d_in[7];
    const float* w_fh = (const float*)d_in[8];
    const float* b_f  = (const float*)d_in[9];
    const float* w_ox = (const float*)d_in[10];
    const float* w_oh = (const float*)d_in[11];
    const float* b_o  = (const float*)d_in[12];
    const float* w_out = (const float*)d_in[13];
    const float* b_out = (const float*)d_in[14];
    float* out = (float*)d_out;

    char* ws = (char*)d_ws;
    size_t off = 0;
    auto alloc = [&](size_t bytes) { void* p = ws + off; off += (bytes + 255) & ~255ull; return p; };
    // flags (16KB) | H0c contiguous -> one zeroing kernel
    unsigned*       flags = (unsigned*)alloc(16384);      // 256 WG-flags, 64B apart
    unsigned short* H0c   = (unsigned short*)alloc((size_t)Bdim * 512 * 2);
    unsigned short* H1c   = (unsigned short*)alloc((size_t)Bdim * 512 * 2);
    float*          Hf32  = (float*)alloc((size_t)Bdim * 512 * 4);
    unsigned short* Whi   = (unsigned short*)alloc(2048ull * Kpad * 2);
    unsigned short* Wlo   = (unsigned short*)alloc(2048ull * Kpad * 2);
    unsigned short* Xhi   = (unsigned short*)alloc((size_t)Tdim * Bdim * 32 * 2);
    unsigned short* Xlo   = (unsigned short*)alloc((size_t)Tdim * Bdim * 32 * 2);
    (void)ws_size; (void)in_sizes; (void)n_in; (void)out_size;

    k_prep_w<<<(2048 * Kpad + 255) / 256, 256, 0, stream>>>(
        w_gh, w_ih, w_fh, w_oh, w_gx, w_ix, w_fx, w_ox, Whi, Wlo);
    k_prep_x<<<(Tdim * Bdim * 32 + 255) / 256, 256, 0, stream>>>(x, Xhi, Xlo);
    // zero flags(16KB)+H0c(256KB): 278,528 B = 69,632 floats = 272 blocks
    k_zero<<<272, 256, 0, stream>>>((float*)flags);

    hipFuncSetAttribute((const void*)k_persist,
                        hipFuncAttributeMaxDynamicSharedMemorySize, LDS_BYTES);
    k_persist<<<dim3(256), dim3(512), LDS_BYTES, stream>>>(
        Whi, Wlo, Xhi, Xlo, H0c, H1c,
        Hf32, b_g, b_i, b_f, b_o, flags);

    k_out<<<256, 64, 0, stream>>>(Hf32, w_out, b_out, out);
}

// Round 24
// 1885.199 us; speedup vs baseline: 1.7810x; 1.7810x over previous
//
#include <hip/hip_runtime.h>

// LSTM H=512, B=256, T=256, D_IN=10, C=10. fp32 in/out.
// R24: ZERO-BARRIER wave-autonomous recurrence. R9 skeleton (col-major h-hi
// exchange, batched agent B-loads - proven codegen) with ALL intra-step sync
// removed. Per-WAVE flags: wave (rg,wm,wn) owns an 8-row x 16-col patch;
// consumer wave's column needs exactly the 64 producer waves of its (ct,wn)
// group -> 64 lanes poll 64 flags in parallel. After its 2 stores each wave
// drains vmcnt(0) and lane0 posts its flag. No __syncthreads in the loop.
// WAR: flag(t+1) certifies step-t loads returned + stores drained; producers
// poll group flags >= t before storing step t -> overwrite-safe by induction.
// Groups (ct,wn) are independent -> drift freely, jitter absorbed.

#define Hdim 512
#define Bdim 256
#define Tdim 256
#define Kpad 544          // 512 (h) + 32 (x: 10 real + 22 zero)
#define LROW 552          // weight LDS row stride (shorts)
#define LDS_BYTES (64 * LROW * 2 * 2)   // 141,312 B -> 1 WG/CU

typedef __bf16 bf16x8 __attribute__((ext_vector_type(8)));
typedef float f32x4 __attribute__((ext_vector_type(4)));
typedef unsigned long long u64;

__device__ __forceinline__ unsigned short f2bf(float f) {
    union { float f; unsigned u; } x; x.f = f;
    unsigned r = x.u + 0x7FFFu + ((x.u >> 16) & 1u);
    return (unsigned short)(r >> 16);
}
__device__ __forceinline__ float bf2f(unsigned short h) {
    union { unsigned u; float f; } x; x.u = ((unsigned)h) << 16;
    return x.f;
}
__device__ __forceinline__ bf16x8 ld8(const unsigned short* p) {
    return *reinterpret_cast<const bf16x8*>(p);
}
__device__ __forceinline__ u64 ldA(const u64* p) {   // coherent 8B load (L3)
    return __hip_atomic_load(p, __ATOMIC_RELAXED, __HIP_MEMORY_SCOPE_AGENT);
}
// write-through 2B store (agent scope -> lands at coherence point)
__device__ __forceinline__ void stH(unsigned short* p, unsigned short v) {
    __hip_atomic_store(p, v, __ATOMIC_RELAXED, __HIP_MEMORY_SCOPE_AGENT);
}
__device__ __forceinline__ f32x4 mfma16(bf16x8 a, bf16x8 b, f32x4 c) {
    return __builtin_amdgcn_mfma_f32_16x16x32_bf16(a, b, c, 0, 0, 0);
}
__device__ __forceinline__ bf16x8 pack2(u64 a, u64 b) {
    union { u64 q[2]; bf16x8 v; } u; u.q[0] = a; u.q[1] = b; return u.v;
}
__device__ __forceinline__ float sigm(float x) { return 1.f / (1.f + __expf(-x)); }
__device__ __forceinline__ float tanh_fast(float x) {
    return 2.f / (1.f + __expf(-2.f * x)) - 1.f;
}

// ---------- prep: stacked gate weights -> bf16 hi/lo, row = 4*i + gate ----------
__global__ void k_prep_w(const float* __restrict__ w_gh, const float* __restrict__ w_ih,
                         const float* __restrict__ w_fh, const float* __restrict__ w_oh,
                         const float* __restrict__ w_gx, const float* __restrict__ w_ix,
                         const float* __restrict__ w_fx, const float* __restrict__ w_ox,
                         unsigned short* __restrict__ Whi, unsigned short* __restrict__ Wlo) {
    int idx = blockIdx.x * 256 + threadIdx.x;
    if (idx >= 2048 * Kpad) return;
    int rw = idx / Kpad;
    int k  = idx % Kpad;
    int gate = rw & 3;
    int i = rw >> 2;
    float v = 0.f;
    if (k < 512) {
        const float* wh = (gate == 0) ? w_gh : (gate == 1) ? w_ih : (gate == 2) ? w_fh : w_oh;
        v = wh[i * 512 + k];
    } else if (k < 522) {
        const float* wx = (gate == 0) ? w_gx : (gate == 1) ? w_ix : (gate == 2) ? w_fx : w_ox;
        v = wx[i * 10 + (k - 512)];
    }
    unsigned short hi = f2bf(v);
    unsigned short lo = f2bf(v - bf2f(hi));
    Whi[idx] = hi;
    Wlo[idx] = lo;
}

// ---------- prep: x -> Xhi/Xlo [t][b][32] ----------
__global__ void k_prep_x(const float* __restrict__ x,
                         unsigned short* __restrict__ Xhi, unsigned short* __restrict__ Xlo) {
    int idx = blockIdx.x * 256 + threadIdx.x;
    if (idx >= Tdim * Bdim * 32) return;
    int j = idx & 31;
    int b = (idx >> 5) & 255;
    int t = idx >> 13;
    float v = 0.f;
    if (j < 10) v = x[(b * Tdim + t) * 10 + j];
    unsigned short hi = f2bf(v);
    unsigned short lo = f2bf(v - bf2f(hi));
    Xhi[idx] = hi;
    Xlo[idx] = lo;
}

__global__ void k_zero(float* __restrict__ p) {
    p[blockIdx.x * 256 + threadIdx.x] = 0.f;
}

// ---------- persistent LSTM ----------
// 256 WGs x 256 thr = 32 rg x 8 ct. WG: 64 stacked rows x 32 cols.
// Wave (wm,wn): stacked rows m0+wm*32..+31, cols bn0+wn*16..+15. Lane: cells
// (i0, colc),(i1, colc) with i0 = rg*16+wm*8+q, i1 = i0+4, colc = bn0+wn*16+lr.
// Wave's h-patch: rows [rg*16+wm*8, +8) x cols [bn0+wn*16, +16).
// Flag group (ct,wn): 64 waves (rg x wm). Lane l polls flag of (rg=l>>1, wm=l&1).
__global__ __launch_bounds__(256, 1) void k_persist(
    const unsigned short* __restrict__ Whi, const unsigned short* __restrict__ Wlo,
    const unsigned short* __restrict__ Xhi, const unsigned short* __restrict__ Xlo,
    unsigned short* H0c, unsigned short* H1c,
    float* __restrict__ Hf32,
    const float* __restrict__ bg, const float* __restrict__ bi,
    const float* __restrict__ bf_, const float* __restrict__ bo,
    unsigned* flags) {
    extern __shared__ unsigned short lds[];
    unsigned short* Lhi = lds;                 // [64][LROW]
    unsigned short* Llo = lds + 64 * LROW;

    const int bid = blockIdx.x;
    const int rg  = bid >> 3;                  // row-group id (0..31)
    const int m0  = rg * 64;                   // stacked-row tile base
    const int ct  = bid & 7;                   // column-group id
    const int bn0 = ct * 32;
    const int tid = threadIdx.x;
    const int lane = tid & 63;
    const int wv = tid >> 6;
    const int wm = wv >> 1, wn = wv & 1;
    const int lr = lane & 15, q = lane >> 4;

    // per-wave flags: group g = ct*2+wn (16 groups); within group idx rg*2+wm.
    // one 64B line per flag: flags[(g*64 + idx) * 16]
    const int g = (ct << 1) + wn;
    unsigned* myflag = flags + (((g << 6) + (rg << 1) + wm) << 4);
    const unsigned* pollp = flags + (((g << 6) + lane) << 4);   // lane l -> (l>>1, l&1)

    // one-time weight staging global -> LDS
    for (int it = tid; it < 64 * 68; it += 256) {
        int r = it / 68, c8 = (it % 68) * 8;
        *(bf16x8*)&Lhi[r * LROW + c8] = ld8(Whi + (size_t)(m0 + r) * Kpad + c8);
        *(bf16x8*)&Llo[r * LROW + c8] = ld8(Wlo + (size_t)(m0 + r) * Kpad + c8);
    }
    __syncthreads();   // weights ready (only barrier in the kernel)

    const int kq = q * 8;
    const int colc = bn0 + wn * 16 + lr;       // this lane's column
    const int row0 = wm * 32;                  // local A-row base for this wave
    const int i0 = rg * 16 + wm * 8 + q;       // h-row of frag0 cell
    const int i1 = i0 + 4;                     // h-row of frag1 cell

    float c0 = 0.f, c1 = 0.f;
    const f32x4 binit0 = { bg[i0], bi[i0], bf_[i0], bo[i0] };
    const f32x4 binit1 = { bg[i1], bi[i1], bf_[i1], bo[i1] };

    const unsigned short* A0h = &Lhi[(row0 + lr) * LROW + kq];
    const unsigned short* A0l = &Llo[(row0 + lr) * LROW + kq];
    const unsigned short* A1h = A0h + 16 * LROW;
    const unsigned short* A1l = A0l + 16 * LROW;

    for (int t = 0; t < Tdim; ++t) {
        const unsigned short* Rh = (t & 1) ? H1c : H0c;   // holds h(t-1)
        unsigned short* Wh = (t & 1) ? H0c : H1c;         // receives h(t)
        const unsigned short* Bp = Rh + (size_t)colc * Hdim + kq;
        const unsigned short* XbH = Xhi + ((size_t)t * Bdim + colc) * 32 + kq;
        const unsigned short* XbL = Xlo + ((size_t)t * Bdim + colc) * 32 + kq;

        // ---- 1. wave-local gate: 64 lanes poll the group's 64 producer flags.
        // flag >= t means that producer completed step t-1 (stores drained AND
        // its step-(t-1) loads returned -> safe to read AND overwrite-safe).
        {
            unsigned v = __hip_atomic_load(pollp, __ATOMIC_RELAXED,
                                           __HIP_MEMORY_SCOPE_AGENT);
            bool ok = (v >= (unsigned)t);
            int guard = 1 << 16;   // bounded: pathological case -> no hang
            while (!ok && --guard) {
                __builtin_amdgcn_s_sleep(1);
                v = __hip_atomic_load(pollp, __ATOMIC_RELAXED,
                                      __HIP_MEMORY_SCOPE_AGENT);
                ok = (v >= (unsigned)t);
            }
        }
        asm volatile("" ::: "memory");   // no B-load hoisting above the gate

        // ---- 2. batched B loads (R9-proven pattern: all 16 in flight) ----
        u64 rbh[16][2];
#pragma unroll
        for (int kb = 0; kb < 16; ++kb) {
            const u64* p0 = (const u64*)(Bp + kb * 32);
            rbh[kb][0] = ldA(p0);
            rbh[kb][1] = ldA(p0 + 1);
        }
        bf16x8 xh = ld8(XbH), xl = ld8(XbL);   // x: read-only cached

        // ---- 3. MFMA: W hi+lo from LDS, B = h-hi regs ----
        f32x4 acc0 = binit0, acc1 = binit1;
#pragma unroll
        for (int kb = 0; kb < 16; ++kb) {
            const int k = kb * 32;
            bf16x8 a0h = ld8(A0h + k), a0l = ld8(A0l + k);
            bf16x8 a1h = ld8(A1h + k), a1l = ld8(A1l + k);
            bf16x8 bh = pack2(rbh[kb][0], rbh[kb][1]);
            acc0 = mfma16(a0h, bh, acc0);
            acc1 = mfma16(a1h, bh, acc1);
            acc0 = mfma16(a0l, bh, acc0);
            acc1 = mfma16(a1l, bh, acc1);
        }
        {   // x tail (k block 16): x keeps hi+lo
            const int k = 512;
            bf16x8 a0h = ld8(A0h + k), a0l = ld8(A0l + k);
            bf16x8 a1h = ld8(A1h + k), a1l = ld8(A1l + k);
            acc0 = mfma16(a0h, xh, acc0);
            acc1 = mfma16(a1h, xh, acc1);
            acc0 = mfma16(a0h, xl, acc0);
            acc1 = mfma16(a1h, xl, acc1);
            acc0 = mfma16(a0l, xh, acc0);
            acc1 = mfma16(a1l, xh, acc1);
        }

        // ---- 4. epilogue: two lane-local cell updates + scattered stores ----
        {   // frag0 cell (i0, colc)
            float gg = tanh_fast(acc0[0]), ii = sigm(acc0[1]);
            float ff = sigm(acc0[2]),      oo = sigm(acc0[3]);
            c0 = gg * ii + c0 * ff;
            float h = tanh_fast(c0) * oo;
            size_t idx = (size_t)colc * Hdim + i0;
            stH(Wh + idx, f2bf(h));
            if (t == Tdim - 1) Hf32[idx] = h;
        }
        {   // frag1 cell (i1, colc)
            float gg = tanh_fast(acc1[0]), ii = sigm(acc1[1]);
            float ff = sigm(acc1[2]),      oo = sigm(acc1[3]);
            c1 = gg * ii + c1 * ff;
            float h = tanh_fast(c1) * oo;
            size_t idx = (size_t)colc * Hdim + i1;
            stH(Wh + idx, f2bf(h));
            if (t == Tdim - 1) Hf32[idx] = h;
        }

        // ---- 5. per-wave drain + flag post (no barrier!) ----
        asm volatile("s_waitcnt vmcnt(0)" ::: "memory");  // this wave's stores acked
        if (lane == 0)
            __hip_atomic_store(myflag, (unsigned)(t + 1),
                               __ATOMIC_RELAXED, __HIP_MEMORY_SCOPE_AGENT);
    }
}

// ---------- output: logits + softmax, one block per batch element ----------
__global__ __launch_bounds__(64) void k_out(
    const float* __restrict__ Hf32, const float* __restrict__ w_out,
    const float* __restrict__ b_out, float* __restrict__ out) {
    int b = blockIdx.x;
    int lane = threadIdx.x;
    const f32x4* h4 = (const f32x4*)(Hf32 + (size_t)b * 512);
    f32x4 h0 = h4[lane * 2], h1 = h4[lane * 2 + 1];
    float acc[10];
#pragma unroll
    for (int c = 0; c < 10; ++c) {
        const f32x4* w4 = (const f32x4*)(w_out + c * 512);
        f32x4 w0 = w4[lane * 2], w1 = w4[lane * 2 + 1];
        acc[c] = h0[0]*w0[0] + h0[1]*w0[1] + h0[2]*w0[2] + h0[3]*w0[3]
               + h1[0]*w1[0] + h1[1]*w1[1] + h1[2]*w1[2] + h1[3]*w1[3];
    }
#pragma unroll
    for (int s = 32; s >= 1; s >>= 1)
#pragma unroll
        for (int c = 0; c < 10; ++c) acc[c] += __shfl_xor(acc[c], s, 64);
    if (lane == 0) {
        float logit[10];
#pragma unroll
        for (int c = 0; c < 10; ++c) logit[c] = acc[c] + b_out[c];
        float m = logit[0];
#pragma unroll
        for (int c = 1; c < 10; ++c) m = fmaxf(m, logit[c]);
        float e[10], sum = 0.f;
#pragma unroll
        for (int c = 0; c < 10; ++c) { e[c] = __expf(logit[c] - m); sum += e[c]; }
        float inv = 1.f / sum;
#pragma unroll
        for (int c = 0; c < 10; ++c) out[b * 10 + c] = e[c] * inv;
    }
}

extern "C" void kernel_launch(void* const* d_in, const int* in_sizes, int n_in,
                              void* d_out, int out_size, void* d_ws, size_t ws_size,
                              hipStream_t stream) {
    const float* x    = (const float*)d_in[0];
    const float* w_gx = (const float*)d_in[1];
    const float* w_gh = (const float*)d_in[2];
    const float* b_g  = (const float*)d_in[3];
    const float* w_ix = (const float*)d_in[4];
    const float* w_ih = (const float*)d_in[5];
    const float* b_i  = (const float*)d_in[6];
    const float* w_fx = (const float*)d_in[7];
    const float* w_fh = (const float*)d_in[8];
    const float* b_f  = (const float*)d_in[9];
    const float* w_ox = (const float*)d_in[10];
    const float* w_oh = (const float*)d_in[11];
    const float* b_o  = (const float*)d_in[12];
    const float* w_out = (const float*)d_in[13];
    const float* b_out = (const float*)d_in[14];
    float* out = (float*)d_out;

    char* ws = (char*)d_ws;
    size_t off = 0;
    auto alloc = [&](size_t bytes) { void* p = ws + off; off += (bytes + 255) & ~255ull; return p; };
    // flags (64KB: 16 groups x 64 wave-flags x 64B) | H0c contiguous -> one zeroing
    unsigned*       flags = (unsigned*)alloc(65536);
    unsigned short* H0c   = (unsigned short*)alloc((size_t)Bdim * 512 * 2);
    unsigned short* H1c   = (unsigned short*)alloc((size_t)Bdim * 512 * 2);
    float*          Hf32  = (float*)alloc((size_t)Bdim * 512 * 4);
    unsigned short* Whi   = (unsigned short*)alloc(2048ull * Kpad * 2);
    unsigned short* Wlo   = (unsigned short*)alloc(2048ull * Kpad * 2);
    unsigned short* Xhi   = (unsigned short*)alloc((size_t)Tdim * Bdim * 32 * 2);
    unsigned short* Xlo   = (unsigned short*)alloc((size_t)Tdim * Bdim * 32 * 2);
    (void)ws_size; (void)in_sizes; (void)n_in; (void)out_size;

    k_prep_w<<<(2048 * Kpad + 255) / 256, 256, 0, stream>>>(
        w_gh, w_ih, w_fh, w_oh, w_gx, w_ix, w_fx, w_ox, Whi, Wlo);
    k_prep_x<<<(Tdim * Bdim * 32 + 255) / 256, 256, 0, stream>>>(x, Xhi, Xlo);
    // zero flags(64KB)+H0c(256KB): 327,680 B = 81,920 floats = 320 blocks
    k_zero<<<320, 256, 0, stream>>>((float*)flags);

    hipFuncSetAttribute((const void*)k_persist,
                        hipFuncAttributeMaxDynamicSharedMemorySize, LDS_BYTES);
    k_persist<<<dim3(256), dim3(256), LDS_BYTES, stream>>>(
        Whi, Wlo, Xhi, Xlo, H0c, H1c,
        Hf32, b_g, b_i, b_f, b_o, flags);

    k_out<<<256, 64, 0, stream>>>(Hf32, w_out, b_out, out);
}

// Round 25
// 1090.134 us; speedup vs baseline: 3.0799x; 1.7293x over previous
//
#include <hip/hip_runtime.h>

// LSTM H=512, B=256, T=256, D_IN=10, C=10. fp32 in/out.
// FINAL = R18 champion (1131us, absmax 4.9e-4), reproduced verbatim.
// 24-round summary: persistent kernel (1 WG/CU via 159KB LDS), gate-interleaved
// stacked weights as bf16 hi/lo in LDS (row = 4*i+gate so each lane's 4 MFMA
// acc regs are {g,i,f,o} of one cell -> lane-local LSTM update), h exchanged
// as bf16-hi through the L3 coherence point with agent-scope relaxed atomics,
// per-WG split flags (A: cols 0-15 posted mid-step, B: cols 16-31 end-of-step)
// + lane-parallel bounded polls, LDS-staged B panel (conflict-managed), h
// stores coalesced via 1KB LDS bounce. Verified dead-ends: threadfence fences
// (R3: 12.9ms), sc0/L2-local exchange (R11: stale L1 polls), load batching
// (R8: latency not BW), traffic cuts (R14/R16: dur-neutral), weights-in-regs
// (R13), 8-wave panel (R22/23: compiler defeats batching), zero-barrier
// wave-autonomous (R24: jitter + flag traffic > barrier cost).

#define Hdim 512
#define Bdim 256
#define Tdim 256
#define Kpad 544          // 512 (h) + 32 (x: 10 real + 22 zero)
#define LROW 552          // weight LDS row stride (shorts)
#define PROW 520          // panel LDS col stride (shorts)
#define LDS_BYTES ((64 * LROW * 2 + 16 * PROW + 512) * 2)   // 158,976 B -> 1 WG/CU

typedef __bf16 bf16x8 __attribute__((ext_vector_type(8)));
typedef float f32x4 __attribute__((ext_vector_type(4)));
typedef unsigned long long u64;

__device__ __forceinline__ unsigned short f2bf(float f) {
    union { float f; unsigned u; } x; x.f = f;
    unsigned r = x.u + 0x7FFFu + ((x.u >> 16) & 1u);
    return (unsigned short)(r >> 16);
}
__device__ __forceinline__ float bf2f(unsigned short h) {
    union { unsigned u; float f; } x; x.u = ((unsigned)h) << 16;
    return x.f;
}
__device__ __forceinline__ bf16x8 ld8(const unsigned short* p) {
    return *reinterpret_cast<const bf16x8*>(p);
}
__device__ __forceinline__ u64 ldA(const u64* p) {   // coherent 8B load (L3)
    return __hip_atomic_load(p, __ATOMIC_RELAXED, __HIP_MEMORY_SCOPE_AGENT);
}
// write-through 4B store (agent scope -> lands at coherence point)
__device__ __forceinline__ void stH32(unsigned* p, unsigned v) {
    __hip_atomic_store(p, v, __ATOMIC_RELAXED, __HIP_MEMORY_SCOPE_AGENT);
}
__device__ __forceinline__ f32x4 mfma16(bf16x8 a, bf16x8 b, f32x4 c) {
    return __builtin_amdgcn_mfma_f32_16x16x32_bf16(a, b, c, 0, 0, 0);
}
__device__ __forceinline__ bf16x8 pack2(u64 a, u64 b) {
    union { u64 q[2]; bf16x8 v; } u; u.q[0] = a; u.q[1] = b; return u.v;
}
__device__ __forceinline__ float sigm(float x) { return 1.f / (1.f + __expf(-x)); }
__device__ __forceinline__ float tanh_fast(float x) {
    return 2.f / (1.f + __expf(-2.f * x)) - 1.f;
}
// poll helper: wave0 lanes 0-31, first check sleepless, bounded
__device__ __forceinline__ void pollFlags(const unsigned* pollp, unsigned tgt, int lane) {
    bool ok = lane >= 32;
    if (!ok) {
        unsigned v = __hip_atomic_load(pollp, __ATOMIC_RELAXED, __HIP_MEMORY_SCOPE_AGENT);
        ok = (v >= tgt);
    }
    int guard = 1 << 16;
    while (!ok && --guard) {
        __builtin_amdgcn_s_sleep(1);
        unsigned v = __hip_atomic_load(pollp, __ATOMIC_RELAXED, __HIP_MEMORY_SCOPE_AGENT);
        ok = (v >= tgt);
    }
}

// ---------- prep: stacked gate weights -> bf16 hi/lo, row = 4*i + gate ----------
__global__ void k_prep_w(const float* __restrict__ w_gh, const float* __restrict__ w_ih,
                         const float* __restrict__ w_fh, const float* __restrict__ w_oh,
                         const float* __restrict__ w_gx, const float* __restrict__ w_ix,
                         const float* __restrict__ w_fx, const float* __restrict__ w_ox,
                         unsigned short* __restrict__ Whi, unsigned short* __restrict__ Wlo) {
    int idx = blockIdx.x * 256 + threadIdx.x;
    if (idx >= 2048 * Kpad) return;
    int rw = idx / Kpad;
    int k  = idx % Kpad;
    int gate = rw & 3;
    int i = rw >> 2;
    float v = 0.f;
    if (k < 512) {
        const float* wh = (gate == 0) ? w_gh : (gate == 1) ? w_ih : (gate == 2) ? w_fh : w_oh;
        v = wh[i * 512 + k];
    } else if (k < 522) {
        const float* wx = (gate == 0) ? w_gx : (gate == 1) ? w_ix : (gate == 2) ? w_fx : w_ox;
        v = wx[i * 10 + (k - 512)];
    }
    unsigned short hi = f2bf(v);
    unsigned short lo = f2bf(v - bf2f(hi));
    Whi[idx] = hi;
    Wlo[idx] = lo;
}

// ---------- prep: x -> Xhi/Xlo [t][b][32] ----------
__global__ void k_prep_x(const float* __restrict__ x,
                         unsigned short* __restrict__ Xhi, unsigned short* __restrict__ Xlo) {
    int idx = blockIdx.x * 256 + threadIdx.x;
    if (idx >= Tdim * Bdim * 32) return;
    int j = idx & 31;
    int b = (idx >> 5) & 255;
    int t = idx >> 13;
    float v = 0.f;
    if (j < 10) v = x[(b * Tdim + t) * 10 + j];
    unsigned short hi = f2bf(v);
    unsigned short lo = f2bf(v - bf2f(hi));
    Xhi[idx] = hi;
    Xlo[idx] = lo;
}

__global__ void k_zero(float* __restrict__ p) {
    p[blockIdx.x * 256 + threadIdx.x] = 0.f;
}

// ---------- persistent LSTM ----------
// 256 WGs x 256 thr. WG: 64 stacked rows x 32 cols. Wave w: rows w*16..+15.
// h layout: Hc[((ct*32+rg)*32 + col_local)*16 + r16] -> 1KB/WG contiguous.
// Flags: flagsA (cols 0-15 stored), flagsB (cols 16-31 stored), 64B lines.
__global__ __launch_bounds__(256, 1) void k_persist(
    const unsigned short* __restrict__ Whi, const unsigned short* __restrict__ Wlo,
    const unsigned short* __restrict__ Xhi, const unsigned short* __restrict__ Xlo,
    unsigned short* H0c, unsigned short* H1c,
    float* __restrict__ Hf32,
    const float* __restrict__ bg, const float* __restrict__ bi,
    const float* __restrict__ bf_, const float* __restrict__ bo,
    unsigned* flags) {
    extern __shared__ unsigned short lds[];
    unsigned short* Lhi = lds;                       // [64][LROW]
    unsigned short* Llo = lds + 64 * LROW;           // [64][LROW]
    unsigned short* Pp  = lds + 64 * LROW * 2;       // [16][PROW] panel
    unsigned short* Ho  = Pp + 16 * PROW;            // [32][16] h-out bounce

    const int bid = blockIdx.x;
    const int rg  = bid >> 3;                  // row-group id (0..31)
    const int m0  = rg * 64;                   // stacked-row tile base
    const int ct  = bid & 7;                   // column-group id
    const int bn0 = ct * 32;
    const int tid = threadIdx.x;
    const int lane = tid & 63;
    const int w  = tid >> 6;                   // wave id: rows w*16..w*16+15
    const int lr = lane & 15, q = lane >> 4;

    // flags: flagsA = flags[0..4095], flagsB = flags[4096..8191] (uints)
    unsigned* flagsA = flags;
    unsigned* flagsB = flags + 4096;
    unsigned* myflagA = flagsA + (((ct << 5) + rg) << 4);
    unsigned* myflagB = flagsB + (((ct << 5) + rg) << 4);
    const unsigned* pollpA = flagsA + (((ct << 5) + (lane & 31)) << 4);
    const unsigned* pollpB = flagsB + (((ct << 5) + (lane & 31)) << 4);

    // panel staging role: thread (cl = tid>>4, e = tid&15)
    const int cl = tid >> 4;
    const int e  = tid & 15;

    // one-time weight staging global -> LDS
    for (int it = tid; it < 64 * 68; it += 256) {
        int r = it / 68, c8 = (it % 68) * 8;
        *(bf16x8*)&Lhi[r * LROW + c8] = ld8(Whi + (size_t)(m0 + r) * Kpad + c8);
        *(bf16x8*)&Llo[r * LROW + c8] = ld8(Wlo + (size_t)(m0 + r) * Kpad + c8);
    }
    __syncthreads();

    const int kq = q * 8;
    const int col0 = bn0 + lr;                 // acc0 cell column (phase A)
    const int col1 = col0 + 16;                // acc1 cell column (phase B)
    const int i0 = rg * 16 + w * 4 + q;        // h-row of both cells
    const int r16 = w * 4 + q;                 // row%16

    float c0 = 0.f, c1 = 0.f;
    const f32x4 binit = { bg[i0], bi[i0], bf_[i0], bo[i0] };

    const unsigned short* Ah = &Lhi[(w * 16 + lr) * LROW + kq];
    const unsigned short* Al = &Llo[(w * 16 + lr) * LROW + kq];
    const unsigned short* Bl = &Pp[lr * PROW + kq];
    unsigned short* Pd0 = &Pp[cl * PROW + e * 16];        // rows of rg=e
    unsigned short* Pd1 = &Pp[cl * PROW + e * 16 + 256];  // rows of rg=e+16

    // global h block base (compact layout)
    const size_t myblk = ((size_t)ct * 32 + rg) * 512;    // this WG's 1KB block

    for (int t = 0; t < Tdim; ++t) {
        const unsigned short* Rh = (t & 1) ? H1c : H0c;   // holds h(t-1)
        unsigned short* Whc = (t & 1) ? H0c : H1c;        // receives h(t)
        const unsigned tgt = (unsigned)t;      // h(t-1) availability generation

        // ---- gate A: h(t-1) cols 0-15 stored (first-try hit in steady state)
        if (w == 0) pollFlags(pollpA, tgt, lane);
        __syncthreads();                       // S0
        asm volatile("" ::: "memory");

        // ---- stageA loads (cols cl of this ct), batched ----
        u64 a0[4], a1[4];
        {
            const u64* s0 = (const u64*)(Rh + (((size_t)ct * 32 + e) * 32 + cl) * 16);
            const u64* s1 = (const u64*)(Rh + (((size_t)ct * 32 + e + 16) * 32 + cl) * 16);
#pragma unroll
            for (int v = 0; v < 4; ++v) a0[v] = ldA(s0 + v);
#pragma unroll
            for (int v = 0; v < 4; ++v) a1[v] = ldA(s1 + v);
        }
        // x fragments (read-only, cached)
        const unsigned short* xb  = Xhi + ((size_t)t * Bdim) * 32;
        const unsigned short* xbl = Xlo + ((size_t)t * Bdim) * 32;
        bf16x8 xh0 = ld8(xb + col0 * 32 + kq), xl0 = ld8(xbl + col0 * 32 + kq);
        bf16x8 xh1 = ld8(xb + col1 * 32 + kq), xl1 = ld8(xbl + col1 * 32 + kq);

        // ---- gate B: h(t-1) cols 16-31 (polled under stageA latency) ----
        if (w == 0) pollFlags(pollpB, tgt, lane);
        __syncthreads();                       // S1
        asm volatile("" ::: "memory");

        // ---- stageB loads issue (latency hidden under MFMA-A) ----
        u64 b0[4], b1[4];
        {
            const u64* s0 = (const u64*)(Rh + (((size_t)ct * 32 + e) * 32 + 16 + cl) * 16);
            const u64* s1 = (const u64*)(Rh + (((size_t)ct * 32 + e + 16) * 32 + 16 + cl) * 16);
#pragma unroll
            for (int v = 0; v < 4; ++v) b0[v] = ldA(s0 + v);
#pragma unroll
            for (int v = 0; v < 4; ++v) b1[v] = ldA(s1 + v);
        }
        // write panel A (stageA data)
        *(bf16x8*)(Pd0)     = pack2(a0[0], a0[1]);
        *(bf16x8*)(Pd0 + 8) = pack2(a0[2], a0[3]);
        *(bf16x8*)(Pd1)     = pack2(a1[0], a1[1]);
        *(bf16x8*)(Pd1 + 8) = pack2(a1[2], a1[3]);
        __syncthreads();                       // S2: panel A ready

        // ---- MFMA phase A (cols 0-15) -> acc0 ----
        f32x4 acc0 = binit, acc1 = binit;
#pragma unroll
        for (int kb = 0; kb < 16; ++kb) {
            const int k = kb * 32;
            bf16x8 ah = ld8(Ah + k), al = ld8(Al + k);
            bf16x8 bh = ld8(Bl + k);
            acc0 = mfma16(ah, bh, acc0);
            acc0 = mfma16(al, bh, acc0);
        }
        {   // x tail acc0
            bf16x8 ah = ld8(Ah + 512), al = ld8(Al + 512);
            acc0 = mfma16(ah, xh0, acc0);
            acc0 = mfma16(ah, xl0, acc0);
            acc0 = mfma16(al, xh0, acc0);
        }
        {   // epilogue A: cell (i0, col0) -> Ho bytes [0,512)
            float g = tanh_fast(acc0[0]), ii = sigm(acc0[1]);
            float f = sigm(acc0[2]),      o  = sigm(acc0[3]);
            c0 = g * ii + c0 * f;
            float h = tanh_fast(c0) * o;
            Ho[lr * 16 + r16] = f2bf(h);
            if (t == Tdim - 1) Hf32[(size_t)col0 * Hdim + i0] = h;
        }
        __syncthreads();                       // S3: panel A consumed + Ho-A done

        // write panel B (stageB data)
        *(bf16x8*)(Pd0)     = pack2(b0[0], b0[1]);
        *(bf16x8*)(Pd0 + 8) = pack2(b0[2], b0[3]);
        *(bf16x8*)(Pd1)     = pack2(b1[0], b1[1]);
        *(bf16x8*)(Pd1 + 8) = pack2(b1[2], b1[3]);
        __syncthreads();                       // S4: panel B ready

        // ---- storeA (coalesced, bytes 0-511 of block) + MFMA-B overlap ----
        if (tid < 128)
            stH32((unsigned*)(Whc + myblk) + tid, *(const unsigned*)&Ho[tid * 2]);

        // ---- MFMA phase B (cols 16-31) -> acc1 (hides storeA latency) ----
#pragma unroll
        for (int kb = 0; kb < 16; ++kb) {
            const int k = kb * 32;
            bf16x8 ah = ld8(Ah + k), al = ld8(Al + k);
            bf16x8 bh = ld8(Bl + k);
            acc1 = mfma16(ah, bh, acc1);
            acc1 = mfma16(al, bh, acc1);
        }
        {   // x tail acc1
            bf16x8 ah = ld8(Ah + 512), al = ld8(Al + 512);
            acc1 = mfma16(ah, xh1, acc1);
            acc1 = mfma16(ah, xl1, acc1);
            acc1 = mfma16(al, xh1, acc1);
        }
        {   // epilogue B: cell (i0, col1) -> Ho bytes [512,1024)
            float g = tanh_fast(acc1[0]), ii = sigm(acc1[1]);
            float f = sigm(acc1[2]),      o  = sigm(acc1[3]);
            c1 = g * ii + c1 * f;
            float h = tanh_fast(c1) * o;
            Ho[(16 + lr) * 16 + r16] = f2bf(h);
            if (t == Tdim - 1) Hf32[(size_t)col1 * Hdim + i0] = h;
        }
        __syncthreads();     // S5: Ho-B done; ALL waves' storeA drained (barrier
                             // implies per-wave vmcnt(0) before s_barrier)
        // ---- post flagA: safe, storeA provably complete ----
        if (tid == 0)
            __hip_atomic_store(myflagA, (unsigned)(t + 1),
                               __ATOMIC_RELAXED, __HIP_MEMORY_SCOPE_AGENT);

        // ---- storeB (bytes 512-1023) ----
        if (tid >= 128)
            stH32((unsigned*)(Whc + myblk) + tid, *(const unsigned*)&Ho[tid * 2]);
        __syncthreads();     // S6: waves 2-3's storeB drained
        // ---- post flagB: safe ----
        if (tid == 0)
            __hip_atomic_store(myflagB, (unsigned)(t + 1),
                               __ATOMIC_RELAXED, __HIP_MEMORY_SCOPE_AGENT);
    }
}

// ---------- output: logits + softmax, one block per batch element ----------
__global__ __launch_bounds__(64) void k_out(
    const float* __restrict__ Hf32, const float* __restrict__ w_out,
    const float* __restrict__ b_out, float* __restrict__ out) {
    int b = blockIdx.x;
    int lane = threadIdx.x;
    const f32x4* h4 = (const f32x4*)(Hf32 + (size_t)b * 512);
    f32x4 h0 = h4[lane * 2], h1 = h4[lane * 2 + 1];
    float acc[10];
#pragma unroll
    for (int c = 0; c < 10; ++c) {
        const f32x4* w4 = (const f32x4*)(w_out + c * 512);
        f32x4 w0 = w4[lane * 2], w1 = w4[lane * 2 + 1];
        acc[c] = h0[0]*w0[0] + h0[1]*w0[1] + h0[2]*w0[2] + h0[3]*w0[3]
               + h1[0]*w1[0] + h1[1]*w1[1] + h1[2]*w1[2] + h1[3]*w1[3];
    }
#pragma unroll
    for (int s = 32; s >= 1; s >>= 1)
#pragma unroll
        for (int c = 0; c < 10; ++c) acc[c] += __shfl_xor(acc[c], s, 64);
    if (lane == 0) {
        float logit[10];
#pragma unroll
        for (int c = 0; c < 10; ++c) logit[c] = acc[c] + b_out[c];
        float m = logit[0];
#pragma unroll
        for (int c = 1; c < 10; ++c) m = fmaxf(m, logit[c]);
        float e[10], sum = 0.f;
#pragma unroll
        for (int c = 0; c < 10; ++c) { e[c] = __expf(logit[c] - m); sum += e[c]; }
        float inv = 1.f / sum;
#pragma unroll
        for (int c = 0; c < 10; ++c) out[b * 10 + c] = e[c] * inv;
    }
}

extern "C" void kernel_launch(void* const* d_in, const int* in_sizes, int n_in,
                              void* d_out, int out_size, void* d_ws, size_t ws_size,
                              hipStream_t stream) {
    const float* x    = (const float*)d_in[0];
    const float* w_gx = (const float*)d_in[1];
    const float* w_gh = (const float*)d_in[2];
    const float* b_g  = (const float*)d_in[3];
    const float* w_ix = (const float*)d_in[4];
    const float* w_ih = (const float*)d_in[5];
    const float* b_i  = (const float*)d_in[6];
    const float* w_fx = (const float*)d_in[7];
    const float* w_fh = (const float*)d_in[8];
    const float* b_f  = (const float*)d_in[9];
    const float* w_ox = (const float*)d_in[10];
    const float* w_oh = (const float*)d_in[11];
    const float* b_o  = (const float*)d_in[12];
    const float* w_out = (const float*)d_in[13];
    const float* b_out = (const float*)d_in[14];
    float* out = (float*)d_out;

    char* ws = (char*)d_ws;
    size_t off = 0;
    auto alloc = [&](size_t bytes) { void* p = ws + off; off += (bytes + 255) & ~255ull; return p; };
    // flags (A+B, 32KB) | H0c contiguous -> one zeroing kernel
    unsigned*       flags = (unsigned*)alloc(32768);      // 2 x 256 WG-flags, 64B apart
    unsigned short* H0c   = (unsigned short*)alloc((size_t)Bdim * 512 * 2);
    unsigned short* H1c   = (unsigned short*)alloc((size_t)Bdim * 512 * 2);
    float*          Hf32  = (float*)alloc((size_t)Bdim * 512 * 4);
    unsigned short* Whi   = (unsigned short*)alloc(2048ull * Kpad * 2);
    unsigned short* Wlo   = (unsigned short*)alloc(2048ull * Kpad * 2);
    unsigned short* Xhi   = (unsigned short*)alloc((size_t)Tdim * Bdim * 32 * 2);
    unsigned short* Xlo   = (unsigned short*)alloc((size_t)Tdim * Bdim * 32 * 2);
    (void)ws_size; (void)in_sizes; (void)n_in; (void)out_size;

    k_prep_w<<<(2048 * Kpad + 255) / 256, 256, 0, stream>>>(
        w_gh, w_ih, w_fh, w_oh, w_gx, w_ix, w_fx, w_ox, Whi, Wlo);
    k_prep_x<<<(Tdim * Bdim * 32 + 255) / 256, 256, 0, stream>>>(x, Xhi, Xlo);
    // zero flags(32KB)+H0c(256KB): 294,912 B = 73,728 floats = 288 blocks
    k_zero<<<288, 256, 0, stream>>>((float*)flags);

    hipFuncSetAttribute((const void*)k_persist,
                        hipFuncAttributeMaxDynamicSharedMemorySize, LDS_BYTES);
    k_persist<<<dim3(256), dim3(256), LDS_BYTES, stream>>>(
        Whi, Wlo, Xhi, Xlo, H0c, H1c,
        Hf32, b_g, b_i, b_f, b_o, flags);

    k_out<<<256, 64, 0, stream>>>(Hf32, w_out, b_out, out);
}